// Round 8
// baseline (3000.580 us; speedup 1.0000x reference)
//
#include <hip/hip_runtime.h>
#include <hip/hip_bf16.h>
#include <cmath>

// CrAKN fused implementation.
// R8: bias_layer software-pipelined: GEMM1(g2+1) issues before mish/GEMM2(g2)
// (in-wave MFMA/VALU overlap). W1 fragments are per-lane register-prefetched
// straight from global (permutation baked into prep layout, distance-1
// lookahead -- unlike R6's zero-lookahead which was latency-bound); W2 stays
// LDS double-buffered (16 KB, 1 barrier/iter). Loop fully unrolled.

namespace {

constexpr int kN   = 512;
constexpr int kD   = 64;
constexpr int kH   = 4;
constexpr int kHD  = 128;
constexpr int kHHD = 512;
constexpr int kFB  = 256;
constexpr int kK   = 100;
constexpr float kEps   = 1e-5f;
constexpr float kScale = 0.08838834764831845f; // 1/sqrt(128)

typedef unsigned short u16;
typedef unsigned int u32;
typedef short bf16x8 __attribute__((ext_vector_type(8)));
typedef float f32x4 __attribute__((ext_vector_type(4)));

// mish(x) = x - 2x*rcp(e*(e+2)+2), e = exp(x)  (exact identity)
__device__ __forceinline__ float mish_f(float x) {
    float e  = __expf(fminf(x, 15.0f));
    float n2 = fmaf(e, e + 2.0f, 2.0f);
    return fmaf(x + x, -__builtin_amdgcn_rcpf(n2), x);
}

__device__ __forceinline__ u32 pk_bf16(float a, float b) {
    union { __hip_bfloat162 v; u32 u; } cv;
    cv.v = __float22bfloat162_rn(make_float2(a, b));
    return cv.u; // a low 16, b high 16
}
__device__ __forceinline__ void split2(float a, float b, u32& hi, u32& lo) {
    hi = pk_bf16(a, b);
    float fa = __uint_as_float(hi << 16);
    float fb = __uint_as_float(hi & 0xFFFF0000u);
    lo = pk_bf16(a - fa, b - fb);
}
__device__ __forceinline__ bf16x8 mk8(u32 a, u32 b, u32 c, u32 d) {
    union { u32 w[4]; bf16x8 v; } cv;
    cv.w[0] = a; cv.w[1] = b; cv.w[2] = c; cv.w[3] = d;
    return cv.v;
}

__device__ __forceinline__ u16 bf16_rne(float f) {
    u32 u = __float_as_uint(f);
    u = u + 0x7FFFu + ((u >> 16) & 1u);
    return (u16)(u >> 16);
}
__device__ __forceinline__ void bf16_split(float f, u16& h, u16& l) {
    h = bf16_rne(f);
    float fh = __uint_as_float((u32)h << 16);
    l = bf16_rne(f - fh);
}

__device__ __forceinline__ void ld4(float* d, const float* s) {
    float4 v = *(const float4*)s;
    d[0] = v.x; d[1] = v.y; d[2] = v.z; d[3] = v.w;
}

// GEMM1 micro-tile: 12 MFMA, A-operands (W1 frags) from registers.
__device__ __forceinline__ void gemm1_12(
    const bf16x8 H[2][2], const bf16x8 L[2][2],
    const bf16x8 Bh[2][2], const bf16x8 Bl[2][2], f32x4 a1[2][2])
{
    #pragma unroll
    for (int mt = 0; mt < 2; ++mt)
        #pragma unroll
        for (int u = 0; u < 2; ++u) a1[mt][u] = (f32x4)0.0f;
    #pragma unroll
    for (int u = 0; u < 2; ++u) {
        #pragma unroll
        for (int mt = 0; mt < 2; ++mt) {
            a1[mt][u] = __builtin_amdgcn_mfma_f32_16x16x32_bf16(H[u][0], Bh[mt][0], a1[mt][u], 0, 0, 0);
            a1[mt][u] = __builtin_amdgcn_mfma_f32_16x16x32_bf16(L[u][0], Bh[mt][0], a1[mt][u], 0, 0, 0);
            a1[mt][u] = __builtin_amdgcn_mfma_f32_16x16x32_bf16(H[u][0], Bl[mt][0], a1[mt][u], 0, 0, 0);
            a1[mt][u] = __builtin_amdgcn_mfma_f32_16x16x32_bf16(H[u][1], Bh[mt][1], a1[mt][u], 0, 0, 0);
            a1[mt][u] = __builtin_amdgcn_mfma_f32_16x16x32_bf16(L[u][1], Bh[mt][1], a1[mt][u], 0, 0, 0);
            a1[mt][u] = __builtin_amdgcn_mfma_f32_16x16x32_bf16(H[u][1], Bl[mt][1], a1[mt][u], 0, 0, 0);
        }
    }
}

// ---------------- embed + LN1, and b0 = amds @ bias_emb ----------------
__global__ __launch_bounds__(64) void embed_kernel(
    const float* __restrict__ nf, const float* __restrict__ amds,
    const float* __restrict__ emb_W, const float* __restrict__ emb_b,
    const float* __restrict__ bemb_W, const float* __restrict__ bemb_b,
    const float* __restrict__ ln1_g, const float* __restrict__ ln1_b,
    float* __restrict__ x, float* __restrict__ b0)
{
    const int n = blockIdx.x;
    const int d = threadIdx.x;
    __shared__ float s_row[kFB];
    #pragma unroll
    for (int r = 0; r < kFB / kD; ++r) s_row[r * kD + d] = nf[n * kFB + r * kD + d];
    __syncthreads();
    float acc = emb_b[d];
    for (int k = 0; k < kFB; ++k) acc = fmaf(s_row[k], emb_W[k * kD + d], acc);
    float mu = acc;
    #pragma unroll
    for (int off = 32; off > 0; off >>= 1) mu += __shfl_xor(mu, off);
    mu *= (1.0f / kD);
    float dv = acc - mu;
    float var = dv * dv;
    #pragma unroll
    for (int off = 32; off > 0; off >>= 1) var += __shfl_xor(var, off);
    var *= (1.0f / kD);
    x[n * kD + d] = dv * rsqrtf(var + kEps) * ln1_g[d] + ln1_b[d];
    __syncthreads();
    s_row[d] = amds[n * kK + d];
    if (d < kK - kD) s_row[kD + d] = amds[n * kK + kD + d];
    __syncthreads();
    float bacc = bemb_b[d];
    for (int k = 0; k < kK; ++k) bacc = fmaf(s_row[k], bemb_W[k * kD + d], bacc);
    b0[n * kD + d] = bacc;
}

// ---------------- bias[i,j,d] = b0[j,d] - b0[i,d] ----------------
__global__ __launch_bounds__(256) void bias_init_kernel(
    const float* __restrict__ b0, float4* __restrict__ bias)
{
    int gid = blockIdx.x * 256 + threadIdx.x;
    int d4 = gid & 15;
    int j  = (gid >> 4) & (kN - 1);
    int i  = gid >> 13;
    const float4* b4 = (const float4*)b0;
    float4 a = b4[j * 16 + d4];
    float4 c = b4[i * 16 + d4];
    bias[gid] = make_float4(a.x - c.x, a.y - c.y, a.z - c.z, a.w - c.w);
}

// ---------------- per-launch weight prep ----------------
// dWp[l][grow][k] from diff_W[l][k][n]: grow = (n&~31) | sr(n&31), where
// sr(b) = ((b>>2)&1)*16 + ((b>>3)&3)*4 + (b&3)  -- the GEMM1->GEMM2
// register-handoff permutation (same map R7 applied at LDS-staging time).
// boutWt[l][d][k] from bout_W[l][k][d] (natural order).
__global__ __launch_bounds__(256) void prep_weights_kernel(
    const float* __restrict__ diff_W, const float* __restrict__ bout_W,
    u16* __restrict__ dWp_hi, u16* __restrict__ dWp_lo,
    u16* __restrict__ boutWt_hi, u16* __restrict__ boutWt_lo)
{
    int gid = blockIdx.x * 256 + threadIdx.x; // 2 * 4 * 32768
    if (gid < 4 * 32768) {
        int e = gid;
        int l = e >> 15;
        int r = e & 32767;
        int k = r >> 9;
        int n = r & 511;
        u16 h, lo;
        bf16_split(diff_W[e], h, lo);
        int b  = n & 31;
        int sr = ((b >> 2) & 1) * 16 + ((b >> 3) & 3) * 4 + (b & 3);
        int row = (n & ~31) | sr;
        int w = l * 32768 + row * 64 + k;
        dWp_hi[w] = h; dWp_lo[w] = lo;
    } else {
        int e = gid - 4 * 32768;
        int l = e >> 15;
        int r = e & 32767;
        int k = r >> 6;
        int d = r & 63;
        u16 h, lo;
        bf16_split(bout_W[e], h, lo);
        int w = l * 32768 + d * 512 + k;
        boutWt_hi[w] = h; boutWt_lo[w] = lo;
    }
}

// ---------------- qkv = x @ qkv_W[l] + qkv_b[l] ----------------
__global__ __launch_bounds__(256) void qkv_kernel(
    const float* __restrict__ x, const float* __restrict__ W,
    const float* __restrict__ b, float* __restrict__ qkv)
{
    const int n = blockIdx.y;
    const int c = blockIdx.x * 256 + threadIdx.x;
    __shared__ float s_x[kD];
    if (threadIdx.x < kD) s_x[threadIdx.x] = x[n * kD + threadIdx.x];
    __syncthreads();
    float acc = b[c];
    #pragma unroll 8
    for (int d = 0; d < kD; ++d) acc = fmaf(s_x[d], W[d * (3 * kHHD) + c], acc);
    qkv[n * (3 * kHHD) + c] = acc;
}

// ---------------- fused pair-bias chain, pipelined (v8) ----------------
// Block = 128 pairs (4 waves x 32). Iteration g2 issues GEMM1(g2+1) (W1 frags
// in registers, loaded from global one iteration ahead) BEFORE mish/GEMM2(g2),
// overlapping the wave's own MFMA and VALU phases. W2 chunks LDS
// double-buffered (16 KB), 1 barrier/iter, same hazard pattern as R7.
__global__ __launch_bounds__(256, 4) void bias_layer_mfma(
    float* __restrict__ bias,
    const u16* __restrict__ dWp_hi, const u16* __restrict__ dWp_lo,
    const u16* __restrict__ boutWt_hi, const u16* __restrict__ boutWt_lo,
    const float* __restrict__ diff_b, const float* __restrict__ bout_b,
    float* __restrict__ diffs)
{
    __shared__ u16 s_w2[2][2][2048]; // 16 KB: [buf][plane][64 rows * 32 u16]

    const int t    = threadIdx.x;
    const int w    = t >> 6;
    const int lane = t & 63;
    const int q    = lane >> 4;    // quad
    const int c    = lane & 15;
    const int pb   = blockIdx.x * 128 + w * 32;  // wave's 32 pairs

    // --- W2 staging indices (same as R7's w2 part)
    const int sb_d   = t >> 2;       // W2 row d (0..63)
    const int sb_k2  = t & 3;        // k granule within 32
    const int w2_dst = sb_d * 32 + (sb_k2 ^ ((sb_d >> 1) & 3)) * 8;
    const u16* g_w2h = boutWt_hi + sb_d * 512 + sb_k2 * 8;
    const u16* g_w2l = boutWt_lo + sb_d * 512 + sb_k2 * 8;

    // --- per-lane W1 fragment base: row (g2*32 + u*16 + c), k = s*32 + q*8
    const u16* g_w1h = dWp_hi + c * 64 + q * 8;
    const u16* g_w1l = dWp_lo + c * 64 + q * 8;

    // --- B-frags: bias^T for two 16-pair tiles, K=64 (kept in regs all loop)
    bf16x8 Bh[2][2], Bl[2][2];
    #pragma unroll
    for (int mt = 0; mt < 2; ++mt) {
        #pragma unroll
        for (int s = 0; s < 2; ++s) {
            const float* src = bias + (long)(pb + mt * 16 + c) * kD + s * 32 + q * 8;
            float4 f0 = *(const float4*)src;
            float4 f1 = *(const float4*)(src + 4);
            u32 h0, l0, h1, l1, h2, l2, h3, l3;
            split2(f0.x, f0.y, h0, l0);
            split2(f0.z, f0.w, h1, l1);
            split2(f1.x, f1.y, h2, l2);
            split2(f1.z, f1.w, h3, l3);
            Bh[mt][s] = mk8(h0, h1, h2, h3);
            Bl[mt][s] = mk8(l0, l1, l2, l3);
        }
    }

    // --- prologue: stage w2(0) -> buf0; load W1(0), W1(1); a1 = GEMM1(0)
    {
        bf16x8 r2 = *(const bf16x8*)g_w2h;
        bf16x8 r3 = *(const bf16x8*)g_w2l;
        *(bf16x8*)&s_w2[0][0][w2_dst] = r2;
        *(bf16x8*)&s_w2[0][1][w2_dst] = r3;
    }
    bf16x8 W1h[2][2], W1l[2][2];   // frags for chunk being GEMM1'd next
    #pragma unroll
    for (int u = 0; u < 2; ++u)
        #pragma unroll
        for (int s = 0; s < 2; ++s) {
            W1h[u][s] = *(const bf16x8*)(g_w1h + u * 1024 + s * 32);
            W1l[u][s] = *(const bf16x8*)(g_w1l + u * 1024 + s * 32);
        }
    f32x4 a1[2][2];
    gemm1_12(W1h, W1l, Bh, Bl, a1);     // a1 = GEMM1(0)
    #pragma unroll
    for (int u = 0; u < 2; ++u)
        #pragma unroll
        for (int s = 0; s < 2; ++s) {   // prefetch W1(1)
            W1h[u][s] = *(const bf16x8*)(g_w1h + 2048 + u * 1024 + s * 32);
            W1l[u][s] = *(const bf16x8*)(g_w1l + 2048 + u * 1024 + s * 32);
        }
    __syncthreads();

    f32x4 acc2[2][4];
    #pragma unroll
    for (int mt = 0; mt < 2; ++mt)
        #pragma unroll
        for (int dg = 0; dg < 4; ++dg) acc2[mt][dg] = (f32x4)0.0f;
    float psum[2][4];
    #pragma unroll
    for (int mt = 0; mt < 2; ++mt)
        #pragma unroll
        for (int h = 0; h < 4; ++h) psum[mt][h] = 0.0f;

    const int sw2 = (c >> 1) & 3;   // W2 read swizzle key
    int cur = 0;

    #pragma unroll
    for (int g2 = 0; g2 < 16; ++g2) {
        // ---- A: pipelined front: stage-loads + GEMM1(g2+1) + W1(g2+2) prefetch
        bf16x8 s2h, s2l;
        f32x4 a1n[2][2];
        if (g2 < 15) {
            s2h = *(const bf16x8*)(g_w2h + (g2 + 1) * 32);
            s2l = *(const bf16x8*)(g_w2l + (g2 + 1) * 32);
            gemm1_12(W1h, W1l, Bh, Bl, a1n);   // GEMM1(g2+1), frees W1 regs
            if (g2 < 14) {
                #pragma unroll
                for (int u = 0; u < 2; ++u)
                    #pragma unroll
                    for (int s = 0; s < 2; ++s) {
                        W1h[u][s] = *(const bf16x8*)(g_w1h + (g2 + 2) * 2048 + u * 1024 + s * 32);
                        W1l[u][s] = *(const bf16x8*)(g_w1l + (g2 + 2) * 2048 + u * 1024 + s * 32);
                    }
            }
        }

        // ---- B: mish + psum + split of a1 (chunk g2); overlaps a1n MFMAs
        const int hd = g2 >> 2;
        bf16x8 Ah[2], Al[2];
        #pragma unroll
        for (int mt = 0; mt < 2; ++mt) {
            u32 hh[2][2], lv[2][2];
            #pragma unroll
            for (int u = 0; u < 2; ++u) {
                float4 db = *(const float4*)(diff_b + g2 * 32 + q * 8 + u * 4);
                float v0 = mish_f(a1[mt][u][0] + db.x);
                float v1 = mish_f(a1[mt][u][1] + db.y);
                float v2 = mish_f(a1[mt][u][2] + db.z);
                float v3 = mish_f(a1[mt][u][3] + db.w);
                psum[mt][hd] += v0 * v0 + v1 * v1 + v2 * v2 + v3 * v3;
                split2(v0, v1, hh[u][0], lv[u][0]);
                split2(v2, v3, hh[u][1], lv[u][1]);
            }
            Ah[mt] = mk8(hh[0][0], hh[0][1], hh[1][0], hh[1][1]);
            Al[mt] = mk8(lv[0][0], lv[0][1], lv[1][0], lv[1][1]);
        }

        // ---- C: GEMM2(g2) from LDS buf cur
        {
            const u16* w2h = &s_w2[cur][0][0];
            const u16* w2l = &s_w2[cur][1][0];
            const int kb2 = (q ^ sw2) * 8;
            #pragma unroll
            for (int dg = 0; dg < 4; ++dg) {
                int bo = dg * 512 + c * 32 + kb2;
                bf16x8 Wh = *(const bf16x8*)(w2h + bo);
                bf16x8 Wl = *(const bf16x8*)(w2l + bo);
                #pragma unroll
                for (int mt = 0; mt < 2; ++mt) {
                    acc2[mt][dg] = __builtin_amdgcn_mfma_f32_16x16x32_bf16(Ah[mt], Wh, acc2[mt][dg], 0, 0, 0);
                    acc2[mt][dg] = __builtin_amdgcn_mfma_f32_16x16x32_bf16(Al[mt], Wh, acc2[mt][dg], 0, 0, 0);
                    acc2[mt][dg] = __builtin_amdgcn_mfma_f32_16x16x32_bf16(Ah[mt], Wl, acc2[mt][dg], 0, 0, 0);
                }
            }
        }

        // ---- D: commit w2(g2+1), flip; advance pipeline regs
        if (g2 < 15) {
            int nb = cur ^ 1;
            *(bf16x8*)&s_w2[nb][0][w2_dst] = s2h;
            *(bf16x8*)&s_w2[nb][1][w2_dst] = s2l;
            __syncthreads();
            cur = nb;
            #pragma unroll
            for (int mt = 0; mt < 2; ++mt)
                #pragma unroll
                for (int u = 0; u < 2; ++u) a1[mt][u] = a1n[mt][u];
        }
    }

    // ---- epilogue: bias tile in place + diffs
    #pragma unroll
    for (int mt = 0; mt < 2; ++mt) {
        #pragma unroll
        for (int dg = 0; dg < 4; ++dg) {
            float bb = bout_b[dg * 16 + c];
            #pragma unroll
            for (int r = 0; r < 4; ++r) {
                float v = mish_f(acc2[mt][dg][r] + bb);
                bias[(long)(pb + mt * 16 + 4 * q + r) * kD + dg * 16 + c] = v;
            }
        }
    }
    const int i  = blockIdx.x >> 2;
    const int jb = (blockIdx.x & 3) * 128 + w * 32;
    #pragma unroll
    for (int mt = 0; mt < 2; ++mt) {
        #pragma unroll
        for (int h = 0; h < 4; ++h) {
            psum[mt][h] += __shfl_xor(psum[mt][h], 16);
            psum[mt][h] += __shfl_xor(psum[mt][h], 32);
        }
        float sv = (q == 0) ? psum[mt][0] : (q == 1) ? psum[mt][1]
                 : (q == 2) ? psum[mt][2] : psum[mt][3];
        diffs[q * (kN * kN) + i * kN + jb + mt * 16 + c] = sqrtf(sv);
    }
}

// ---------------- logits[h,n,m] = scale*q.k + diffs ----------------
__global__ __launch_bounds__(256) void logits_kernel(
    const float* __restrict__ qkv, const float* __restrict__ diffs,
    float* __restrict__ logits)
{
    constexpr int SW = 68;
    __shared__ float s_q[64 * SW];
    __shared__ float s_k[64 * SW];
    const int t  = threadIdx.x;
    const int tX = t & 15;
    const int tY = t >> 4;
    const int h  = blockIdx.z;
    const int n0 = blockIdx.x * 64;
    const int m0 = blockIdx.y * 64;

    float acc[4][4];
    #pragma unroll
    for (int a = 0; a < 4; ++a)
        #pragma unroll
        for (int b = 0; b < 4; ++b) acc[a][b] = 0.0f;

    for (int dc = 0; dc < 2; ++dc) {
        __syncthreads();
        #pragma unroll
        for (int rep = 0; rep < 4; ++rep) {
            int f = rep * 256 + t;
            int row = f >> 4;
            int c4  = f & 15;
            *(float4*)&s_q[row * SW + c4 * 4] =
                *(const float4*)&qkv[(n0 + row) * (3 * kHHD) + h * 384 + dc * 64 + c4 * 4];
            *(float4*)&s_k[row * SW + c4 * 4] =
                *(const float4*)&qkv[(m0 + row) * (3 * kHHD) + h * 384 + 128 + dc * 64 + c4 * 4];
        }
        __syncthreads();
        for (int d = 0; d < 64; d += 4) {
            float a[4][4], b[4][4];
            #pragma unroll
            for (int rr = 0; rr < 4; ++rr) ld4(a[rr], &s_q[(tY + 16 * rr) * SW + d]);
            #pragma unroll
            for (int cc = 0; cc < 4; ++cc) ld4(b[cc], &s_k[(tX + 16 * cc) * SW + d]);
            #pragma unroll
            for (int rr = 0; rr < 4; ++rr)
                #pragma unroll
                for (int cc = 0; cc < 4; ++cc)
                    #pragma unroll
                    for (int u = 0; u < 4; ++u)
                        acc[rr][cc] = fmaf(a[rr][u], b[cc][u], acc[rr][cc]);
        }
    }
    #pragma unroll
    for (int rr = 0; rr < 4; ++rr)
        #pragma unroll
        for (int cc = 0; cc < 4; ++cc) {
            int row = n0 + tY + 16 * rr;
            int col = m0 + tX + 16 * cc;
            long idx = (long)h * (kN * kN) + (long)row * kN + col;
            logits[idx] = acc[rr][cc] * kScale + diffs[idx];
        }
}

// ---------------- softmax over m, per (h,n) row ----------------
__global__ __launch_bounds__(256) void softmax_kernel(float* __restrict__ logits)
{
    const int row = blockIdx.x;
    float* p = logits + (long)row * kN;
    const int t = threadIdx.x;
    float v0 = p[t];
    float v1 = p[t + 256];
    float m = fmaxf(v0, v1);
    #pragma unroll
    for (int off = 32; off > 0; off >>= 1) m = fmaxf(m, __shfl_xor(m, off));
    __shared__ float s_red[4];
    __shared__ float s_sum[4];
    if ((t & 63) == 0) s_red[t >> 6] = m;
    __syncthreads();
    m = fmaxf(fmaxf(s_red[0], s_red[1]), fmaxf(s_red[2], s_red[3]));
    float e0 = expf(v0 - m);
    float e1 = expf(v1 - m);
    float s = e0 + e1;
    #pragma unroll
    for (int off = 32; off > 0; off >>= 1) s += __shfl_xor(s, off);
    if ((t & 63) == 0) s_sum[t >> 6] = s;
    __syncthreads();
    s = (s_sum[0] + s_sum[1]) + (s_sum[2] + s_sum[3]);
    float inv = 1.0f / s;
    p[t] = e0 * inv;
    p[t + 256] = e1 * inv;
}

// ---------------- vals[n, h*128+d] = sum_m attn[h,n,m]*v[m,h,d] -------------
__global__ __launch_bounds__(256) void attnv_kernel(
    const float* __restrict__ attn, const float* __restrict__ qkv,
    float* __restrict__ vals)
{
    constexpr int SW = 68;
    __shared__ float s_p[32 * SW];
    __shared__ float s_v[64 * SW];
    const int t  = threadIdx.x;
    const int tx = t & 15;
    const int ty = t >> 4;
    const int h  = blockIdx.z;
    const int n0 = blockIdx.x * 32;
    const int d0 = blockIdx.y * 64;

    float acc[2][4];
    #pragma unroll
    for (int a = 0; a < 2; ++a)
        #pragma unroll
        for (int b = 0; b < 4; ++b) acc[a][b] = 0.0f;

    for (int mt = 0; mt < 8; ++mt) {
        const int m0 = mt * 64;
        __syncthreads();
        #pragma unroll
        for (int rep = 0; rep < 2; ++rep) {
            int f = rep * 256 + t;
            int row = f >> 4;
            int c4  = f & 15;
            *(float4*)&s_p[row * SW + c4 * 4] =
                *(const float4*)&attn[(long)h * (kN * kN) + (long)(n0 + row) * kN + m0 + c4 * 4];
        }
        #pragma unroll
        for (int rep = 0; rep < 4; ++rep) {
            int f = rep * 256 + t;
            int row = f >> 4;
            int c4  = f & 15;
            *(float4*)&s_v[row * SW + c4 * 4] =
                *(const float4*)&qkv[(m0 + row) * (3 * kHHD) + h * 384 + 256 + d0 + c4 * 4];
        }
        __syncthreads();
        for (int kk = 0; kk < 64; kk += 4) {
            float a[2][4], b[4][4];
            #pragma unroll
            for (int rr = 0; rr < 2; ++rr) ld4(a[rr], &s_p[(ty + 16 * rr) * SW + kk]);
            #pragma unroll
            for (int u = 0; u < 4; ++u) ld4(b[u], &s_v[(kk + u) * SW + 4 * tx]);
            #pragma unroll
            for (int rr = 0; rr < 2; ++rr)
                #pragma unroll
                for (int cc = 0; cc < 4; ++cc)
                    #pragma unroll
                    for (int u = 0; u < 4; ++u)
                        acc[rr][cc] = fmaf(a[rr][u], b[u][cc], acc[rr][cc]);
        }
    }
    #pragma unroll
    for (int rr = 0; rr < 2; ++rr) {
        float4 o = make_float4(acc[rr][0], acc[rr][1], acc[rr][2], acc[rr][3]);
        *(float4*)&vals[(long)(n0 + ty + 16 * rr) * kHHD + h * kHD + d0 + 4 * tx] = o;
    }
}

// ---------------- x = LN2(x + vals@o_W + o_b) ----------------
__global__ __launch_bounds__(64) void oproj_ln_kernel(
    const float* __restrict__ vals, const float* __restrict__ o_W,
    const float* __restrict__ o_b, const float* __restrict__ g2,
    const float* __restrict__ b2, float* __restrict__ x)
{
    const int n = blockIdx.x;
    const int d = threadIdx.x;
    __shared__ float s_v[kHHD];
    #pragma unroll
    for (int r = 0; r < kHHD / kD; ++r) s_v[r * kD + d] = vals[n * kHHD + r * kD + d];
    __syncthreads();
    float acc = o_b[d];
    for (int j = 0; j < kHHD; ++j) acc = fmaf(s_v[j], o_W[j * kD + d], acc);
    float xv = x[n * kD + d] + acc;
    float mu = xv;
    #pragma unroll
    for (int off = 32; off > 0; off >>= 1) mu += __shfl_xor(mu, off);
    mu *= (1.0f / kD);
    float dv = xv - mu;
    float var = dv * dv;
    #pragma unroll
    for (int off = 32; off > 0; off >>= 1) var += __shfl_xor(var, off);
    var *= (1.0f / kD);
    x[n * kD + d] = dv * rsqrtf(var + kEps) * g2[d] + b2[d];
}

// ---------------- out = x @ out_W + out_b ----------------
__global__ __launch_bounds__(64) void final_kernel(
    const float* __restrict__ x, const float* __restrict__ out_W,
    const float* __restrict__ out_b, float* __restrict__ out)
{
    const int n = blockIdx.x * 64 + threadIdx.x;
    float acc = out_b[0];
    #pragma unroll
    for (int d = 0; d < kD; ++d) acc = fmaf(x[n * kD + d], out_W[d], acc);
    out[n] = acc;
}

} // anonymous namespace

extern "C" void kernel_launch(void* const* d_in, const int* in_sizes, int n_in,
                              void* d_out, int out_size, void* d_ws, size_t ws_size,
                              hipStream_t stream)
{
    (void)in_sizes; (void)n_in; (void)out_size; (void)ws_size;

    const float* nf     = (const float*)d_in[0];
    const float* amds   = (const float*)d_in[1];
    const float* emb_W  = (const float*)d_in[2];
    const float* emb_b  = (const float*)d_in[3];
    const float* bemb_W = (const float*)d_in[4];
    const float* bemb_b = (const float*)d_in[5];
    const float* ln1_g  = (const float*)d_in[6];
    const float* ln1_b  = (const float*)d_in[7];
    const float* ln2_g  = (const float*)d_in[8];
    const float* ln2_b  = (const float*)d_in[9];
    const float* qkv_W  = (const float*)d_in[10];
    const float* qkv_b  = (const float*)d_in[11];
    const float* diff_W = (const float*)d_in[12];
    const float* diff_b = (const float*)d_in[13];
    const float* o_W    = (const float*)d_in[14];
    const float* o_b    = (const float*)d_in[15];
    const float* bout_W = (const float*)d_in[16];
    const float* bout_b = (const float*)d_in[17];
    const float* out_W  = (const float*)d_in[18];
    const float* out_b  = (const float*)d_in[19];

    float* ws = (float*)d_ws;
    float* ws_x      = ws;                   // 512*64
    float* ws_b0     = ws_x + 32768;         // 512*64
    float* ws_qkv    = ws_b0 + 32768;        // 512*1536
    float* ws_vals   = ws_qkv + 786432;      // 512*512
    float* ws_diffs  = ws_vals + 262144;     // 4*512*512
    float* ws_logits = ws_diffs + 1048576;   // 4*512*512
    float* ws_bias   = ws_logits + 1048576;  // 512*512*64
    u16*   ws_u      = (u16*)(ws_bias + 16777216);
    u16* dWp_hi    = ws_u;                   // 4*512*64
    u16* dWp_lo    = dWp_hi + 131072;
    u16* boutWt_hi = dWp_lo + 131072;        // 4*64*512
    u16* boutWt_lo = boutWt_hi + 131072;

    embed_kernel<<<kN, kD, 0, stream>>>(nf, amds, emb_W, emb_b, bemb_W, bemb_b,
                                        ln1_g, ln1_b, ws_x, ws_b0);
    bias_init_kernel<<<(kN * kN * kD / 4) / 256, 256, 0, stream>>>(
        ws_b0, (float4*)ws_bias);
    prep_weights_kernel<<<(2 * 4 * 32768) / 256, 256, 0, stream>>>(
        diff_W, bout_W, dWp_hi, dWp_lo, boutWt_hi, boutWt_lo);

    for (int l = 0; l < 4; ++l) {
        qkv_kernel<<<dim3(6, kN), 256, 0, stream>>>(
            ws_x, qkv_W + l * kD * (3 * kHHD), qkv_b + l * (3 * kHHD), ws_qkv);
        bias_layer_mfma<<<kN * kN / 128, 256, 0, stream>>>(
            ws_bias, dWp_hi + l * 32768, dWp_lo + l * 32768,
            boutWt_hi + l * 32768, boutWt_lo + l * 32768,
            diff_b + l * kHHD, bout_b + l * kD, ws_diffs);
        logits_kernel<<<dim3(8, 8, kH), 256, 0, stream>>>(ws_qkv, ws_diffs, ws_logits);
        softmax_kernel<<<kH * kN, 256, 0, stream>>>(ws_logits);
        attnv_kernel<<<dim3(16, 2, kH), 256, 0, stream>>>(ws_logits, ws_qkv, ws_vals);
        oproj_ln_kernel<<<kN, kD, 0, stream>>>(
            ws_vals, o_W + l * kHHD * kD, o_b + l * kD, ln2_g, ln2_b, ws_x);
    }
    final_kernel<<<kN / kD, kD, 0, stream>>>(ws_x, out_W, out_b, (float*)d_out);
}

// Round 9
// 687.749 us; speedup vs baseline: 4.3629x; 4.3629x over previous
//
#include <hip/hip_runtime.h>
#include <hip/hip_bf16.h>
#include <hip/hip_fp16.h>
#include <cmath>

// CrAKN fused implementation.
// R9 = R7 structure with the bias-chain GEMMs in single-pass fp16 (11-bit
// significand, ~2^-10 rel err) instead of bf16x3: 16 MFMA/chunk instead of
// 48, no lo-plane split work, half the weight LDS. The 16x16x32 C/D -> A
// register handoff (W1^T row permutation) is dtype-independent and unchanged.
// R8's pipelined variant spilled to scratch (WRITE_SIZE 1.6 GB) - reverted.

namespace {

constexpr int kN   = 512;
constexpr int kD   = 64;
constexpr int kH   = 4;
constexpr int kHD  = 128;
constexpr int kHHD = 512;
constexpr int kFB  = 256;
constexpr int kK   = 100;
constexpr float kEps   = 1e-5f;
constexpr float kScale = 0.08838834764831845f; // 1/sqrt(128)

typedef unsigned short u16;
typedef unsigned int u32;
typedef short bf16x8 __attribute__((ext_vector_type(8)));   // raw 16B container
typedef _Float16 f16x8 __attribute__((ext_vector_type(8)));
typedef float f32x4 __attribute__((ext_vector_type(4)));

// mish(x) = x - 2x*rcp(e*(e+2)+2), e = exp(x)  (exact identity)
__device__ __forceinline__ float mish_f(float x) {
    float e  = __expf(fminf(x, 15.0f));
    float n2 = fmaf(e, e + 2.0f, 2.0f);
    return fmaf(x + x, -__builtin_amdgcn_rcpf(n2), x);
}

__device__ __forceinline__ u32 pkh(float a, float b) {
    union { __half2 h; u32 u; } cv;
    cv.h = __float22half2_rn(make_float2(a, b));
    return cv.u; // a low 16, b high 16
}
__device__ __forceinline__ f16x8 mkh8(u32 a, u32 b, u32 c, u32 d) {
    union { u32 w[4]; f16x8 v; } cv;
    cv.w[0] = a; cv.w[1] = b; cv.w[2] = c; cv.w[3] = d;
    return cv.v;
}
__device__ __forceinline__ u16 f16_bits(float f) {
    union { __half h; u16 u; } cv;
    cv.h = __float2half(f);
    return cv.u;
}

__device__ __forceinline__ void ld4(float* d, const float* s) {
    float4 v = *(const float4*)s;
    d[0] = v.x; d[1] = v.y; d[2] = v.z; d[3] = v.w;
}

// ---------------- embed + LN1, and b0 = amds @ bias_emb ----------------
__global__ __launch_bounds__(64) void embed_kernel(
    const float* __restrict__ nf, const float* __restrict__ amds,
    const float* __restrict__ emb_W, const float* __restrict__ emb_b,
    const float* __restrict__ bemb_W, const float* __restrict__ bemb_b,
    const float* __restrict__ ln1_g, const float* __restrict__ ln1_b,
    float* __restrict__ x, float* __restrict__ b0)
{
    const int n = blockIdx.x;
    const int d = threadIdx.x;
    __shared__ float s_row[kFB];
    #pragma unroll
    for (int r = 0; r < kFB / kD; ++r) s_row[r * kD + d] = nf[n * kFB + r * kD + d];
    __syncthreads();
    float acc = emb_b[d];
    for (int k = 0; k < kFB; ++k) acc = fmaf(s_row[k], emb_W[k * kD + d], acc);
    float mu = acc;
    #pragma unroll
    for (int off = 32; off > 0; off >>= 1) mu += __shfl_xor(mu, off);
    mu *= (1.0f / kD);
    float dv = acc - mu;
    float var = dv * dv;
    #pragma unroll
    for (int off = 32; off > 0; off >>= 1) var += __shfl_xor(var, off);
    var *= (1.0f / kD);
    x[n * kD + d] = dv * rsqrtf(var + kEps) * ln1_g[d] + ln1_b[d];
    __syncthreads();
    s_row[d] = amds[n * kK + d];
    if (d < kK - kD) s_row[kD + d] = amds[n * kK + kD + d];
    __syncthreads();
    float bacc = bemb_b[d];
    for (int k = 0; k < kK; ++k) bacc = fmaf(s_row[k], bemb_W[k * kD + d], bacc);
    b0[n * kD + d] = bacc;
}

// ---------------- bias[i,j,d] = b0[j,d] - b0[i,d] ----------------
__global__ __launch_bounds__(256) void bias_init_kernel(
    const float* __restrict__ b0, float4* __restrict__ bias)
{
    int gid = blockIdx.x * 256 + threadIdx.x;
    int d4 = gid & 15;
    int j  = (gid >> 4) & (kN - 1);
    int i  = gid >> 13;
    const float4* b4 = (const float4*)b0;
    float4 a = b4[j * 16 + d4];
    float4 c = b4[i * 16 + d4];
    bias[gid] = make_float4(a.x - c.x, a.y - c.y, a.z - c.z, a.w - c.w);
}

// ---------------- per-launch weight prep: transpose + fp16 ----------------
// dWt[l][n][k]  (n<512, k<64)  from diff_W[l][k][n]
// boutWt[l][d][k] (d<64, k<512) from bout_W[l][k][d]
__global__ __launch_bounds__(256) void prep_weights_kernel(
    const float* __restrict__ diff_W, const float* __restrict__ bout_W,
    u16* __restrict__ dWt, u16* __restrict__ boutWt)
{
    int gid = blockIdx.x * 256 + threadIdx.x; // 2 * 4 * 32768
    if (gid < 4 * 32768) {
        int e = gid;
        int l = e >> 15;
        int r = e & 32767;
        int k = r >> 9;
        int n = r & 511;
        dWt[l * 32768 + n * 64 + k] = f16_bits(diff_W[e]);
    } else {
        int e = gid - 4 * 32768;
        int l = e >> 15;
        int r = e & 32767;
        int k = r >> 6;
        int d = r & 63;
        boutWt[l * 32768 + d * 512 + k] = f16_bits(bout_W[e]);
    }
}

// ---------------- qkv = x @ qkv_W[l] + qkv_b[l] ----------------
__global__ __launch_bounds__(256) void qkv_kernel(
    const float* __restrict__ x, const float* __restrict__ W,
    const float* __restrict__ b, float* __restrict__ qkv)
{
    const int n = blockIdx.y;
    const int c = blockIdx.x * 256 + threadIdx.x;
    __shared__ float s_x[kD];
    if (threadIdx.x < kD) s_x[threadIdx.x] = x[n * kD + threadIdx.x];
    __syncthreads();
    float acc = b[c];
    #pragma unroll 8
    for (int d = 0; d < kD; ++d) acc = fmaf(s_x[d], W[d * (3 * kHHD) + c], acc);
    qkv[n * (3 * kHHD) + c] = acc;
}

// ---------------- fused pair-bias chain, fp16 MFMA (R7 structure) ----------
// Block = 128 pairs (4 waves x 32). Per 32-becol group-pair g2:
//   GEMM1 (be^T): A = W1^T rows permuted so that the C output at lane (q,c),
//   tile u, reg r holds be[pair=c][bc = 32*g2 + 8q + 4u + r] -- exactly the
//   A-fragment element k=quad*8+j (j=4u+r) for GEMM2 (16x16x32, layout is
//   dtype-independent).  GEMM2: acc2 += be_chunk @ W2 chunk.
// LDS stages W1/W2 fp16 chunks (XOR-swizzled, double-buffered), 1 barrier/g2.
__global__ __launch_bounds__(256, 4) void bias_layer_mfma(
    float* __restrict__ bias,
    const u16* __restrict__ dWt, const u16* __restrict__ boutWt,
    const float* __restrict__ diff_b, const float* __restrict__ bout_b,
    float* __restrict__ diffs)
{
    // [buf][ w1: 32 rows * 64 u16 | w2 at 2048: 64 rows * 32 u16 ]
    __shared__ u16 s_w[2][4096]; // 16 KB

    const int t    = threadIdx.x;
    const int w    = t >> 6;
    const int lane = t & 63;
    const int q    = lane >> 4;    // quad
    const int c    = lane & 15;
    const int pb   = blockIdx.x * 128 + w * 32;  // wave's 32 pairs

    // --- staging indices (per thread): W1 row-permuted + k-block XOR swizzle
    const int sb_bc  = t >> 3;       // source W1^T row within chunk (0..31)
    const int sb_kb  = t & 7;        // k block (8 u16 each)
    const int sr     = ((sb_bc >> 2) & 1) * 16 + ((sb_bc >> 3) << 2) + (sb_bc & 3);
    const int w1_dst = sr * 64 + (sb_kb ^ (sr & 7)) * 8;
    const int sb_d   = t >> 2;       // W2 row d (0..63)
    const int sb_k2  = t & 3;        // k block within 32
    const int w2_dst = 2048 + sb_d * 32 + (sb_k2 ^ ((sb_d >> 1) & 3)) * 8;
    const u16* g_w1 = dWt + sb_bc * 64 + sb_kb * 8;
    const u16* g_w2 = boutWt + sb_d * 512 + sb_k2 * 8;

    // --- B-frags: bias^T (fp16) for two 16-pair tiles, K=64 (regs all loop)
    f16x8 Bf[2][2];
    #pragma unroll
    for (int mt = 0; mt < 2; ++mt) {
        #pragma unroll
        for (int s = 0; s < 2; ++s) {
            const float* src = bias + (long)(pb + mt * 16 + c) * kD + s * 32 + q * 8;
            float4 f0 = *(const float4*)src;
            float4 f1 = *(const float4*)(src + 4);
            Bf[mt][s] = mkh8(pkh(f0.x, f0.y), pkh(f0.z, f0.w),
                             pkh(f1.x, f1.y), pkh(f1.z, f1.w));
        }
    }

    // --- prologue stage g2=0 into buf 0
    {
        bf16x8 r0 = *(const bf16x8*)g_w1;
        bf16x8 r1 = *(const bf16x8*)g_w2;
        *(bf16x8*)&s_w[0][w1_dst] = r0;
        *(bf16x8*)&s_w[0][w2_dst] = r1;
    }
    __syncthreads();

    f32x4 acc2[2][4];
    #pragma unroll
    for (int mt = 0; mt < 2; ++mt)
        #pragma unroll
        for (int dg = 0; dg < 4; ++dg) acc2[mt][dg] = (f32x4)0.0f;
    float psum[2][4];
    #pragma unroll
    for (int mt = 0; mt < 2; ++mt)
        #pragma unroll
        for (int h = 0; h < 4; ++h) psum[mt][h] = 0.0f;

    const int sw1 = c & 7;          // W1 read swizzle key
    const int sw2 = (c >> 1) & 3;   // W2 read swizzle key
    int cur = 0;

    for (int g2 = 0; g2 < 16; ++g2) {
        // prefetch next weight chunk into regs (committed after compute)
        bf16x8 r0, r1;
        if (g2 < 15) {
            r0 = *(const bf16x8*)(g_w1 + (g2 + 1) * 2048);
            r1 = *(const bf16x8*)(g_w2 + (g2 + 1) * 32);
        }

        // ---- GEMM1: a1[mt][u] = W1^T(permuted rows) x bias^T  (fp16)
        f32x4 a1[2][2];
        #pragma unroll
        for (int mt = 0; mt < 2; ++mt)
            #pragma unroll
            for (int u = 0; u < 2; ++u) a1[mt][u] = (f32x4)0.0f;
        const u16* w1 = &s_w[cur][0];
        #pragma unroll
        for (int u = 0; u < 2; ++u) {
            int row = (u * 16 + c) * 64;
            int o0 = row + ((0 + q) ^ sw1) * 8; // s=0 (k 0..31)
            int o1 = row + ((4 + q) ^ sw1) * 8; // s=1 (k 32..63)
            f16x8 A0 = *(const f16x8*)(w1 + o0);
            f16x8 A1 = *(const f16x8*)(w1 + o1);
            #pragma unroll
            for (int mt = 0; mt < 2; ++mt) {
                a1[mt][u] = __builtin_amdgcn_mfma_f32_16x16x32_f16(A0, Bf[mt][0], a1[mt][u], 0, 0, 0);
                a1[mt][u] = __builtin_amdgcn_mfma_f32_16x16x32_f16(A1, Bf[mt][1], a1[mt][u], 0, 0, 0);
            }
        }

        // ---- mish + psum + fp16 pack; C-layout IS GEMM2 A-layout (j = 4u+r)
        const int hd = g2 >> 2;
        f16x8 A2[2];
        #pragma unroll
        for (int mt = 0; mt < 2; ++mt) {
            u32 p[2][2];
            #pragma unroll
            for (int u = 0; u < 2; ++u) {
                float4 db = *(const float4*)(diff_b + g2 * 32 + q * 8 + u * 4);
                float v0 = mish_f(a1[mt][u][0] + db.x);
                float v1 = mish_f(a1[mt][u][1] + db.y);
                float v2 = mish_f(a1[mt][u][2] + db.z);
                float v3 = mish_f(a1[mt][u][3] + db.w);
                psum[mt][hd] += v0 * v0 + v1 * v1 + v2 * v2 + v3 * v3;
                p[u][0] = pkh(v0, v1);
                p[u][1] = pkh(v2, v3);
            }
            A2[mt] = mkh8(p[0][0], p[0][1], p[1][0], p[1][1]);
        }

        // ---- GEMM2: acc2 += be_chunk @ W2 chunk (fp16)
        const u16* w2 = &s_w[cur][2048];
        const int kb2 = (q ^ sw2) * 8;
        #pragma unroll
        for (int dg = 0; dg < 4; ++dg) {
            int bo = dg * 512 + c * 32 + kb2;
            f16x8 Wf = *(const f16x8*)(w2 + bo);
            #pragma unroll
            for (int mt = 0; mt < 2; ++mt) {
                acc2[mt][dg] = __builtin_amdgcn_mfma_f32_16x16x32_f16(A2[mt], Wf, acc2[mt][dg], 0, 0, 0);
            }
        }

        // ---- commit prefetched chunk, flip buffers
        if (g2 < 15) {
            int nb = cur ^ 1;
            *(bf16x8*)&s_w[nb][w1_dst] = r0;
            *(bf16x8*)&s_w[nb][w2_dst] = r1;
            __syncthreads();
            cur = nb;
        }
    }

    // ---- epilogue: bias tile in place + diffs
    #pragma unroll
    for (int mt = 0; mt < 2; ++mt) {
        #pragma unroll
        for (int dg = 0; dg < 4; ++dg) {
            float bb = bout_b[dg * 16 + c];
            #pragma unroll
            for (int r = 0; r < 4; ++r) {
                float v = mish_f(acc2[mt][dg][r] + bb);
                bias[(long)(pb + mt * 16 + 4 * q + r) * kD + dg * 16 + c] = v;
            }
        }
    }
    const int i  = blockIdx.x >> 2;
    const int jb = (blockIdx.x & 3) * 128 + w * 32;
    #pragma unroll
    for (int mt = 0; mt < 2; ++mt) {
        #pragma unroll
        for (int h = 0; h < 4; ++h) {
            psum[mt][h] += __shfl_xor(psum[mt][h], 16);
            psum[mt][h] += __shfl_xor(psum[mt][h], 32);
        }
        float sv = (q == 0) ? psum[mt][0] : (q == 1) ? psum[mt][1]
                 : (q == 2) ? psum[mt][2] : psum[mt][3];
        diffs[q * (kN * kN) + i * kN + jb + mt * 16 + c] = sqrtf(sv);
    }
}

// ---------------- logits[h,n,m] = scale*q.k + diffs ----------------
__global__ __launch_bounds__(256) void logits_kernel(
    const float* __restrict__ qkv, const float* __restrict__ diffs,
    float* __restrict__ logits)
{
    constexpr int SW = 68;
    __shared__ float s_q[64 * SW];
    __shared__ float s_k[64 * SW];
    const int t  = threadIdx.x;
    const int tX = t & 15;
    const int tY = t >> 4;
    const int h  = blockIdx.z;
    const int n0 = blockIdx.x * 64;
    const int m0 = blockIdx.y * 64;

    float acc[4][4];
    #pragma unroll
    for (int a = 0; a < 4; ++a)
        #pragma unroll
        for (int b = 0; b < 4; ++b) acc[a][b] = 0.0f;

    for (int dc = 0; dc < 2; ++dc) {
        __syncthreads();
        #pragma unroll
        for (int rep = 0; rep < 4; ++rep) {
            int f = rep * 256 + t;
            int row = f >> 4;
            int c4  = f & 15;
            *(float4*)&s_q[row * SW + c4 * 4] =
                *(const float4*)&qkv[(n0 + row) * (3 * kHHD) + h * 384 + dc * 64 + c4 * 4];
            *(float4*)&s_k[row * SW + c4 * 4] =
                *(const float4*)&qkv[(m0 + row) * (3 * kHHD) + h * 384 + 128 + dc * 64 + c4 * 4];
        }
        __syncthreads();
        for (int d = 0; d < 64; d += 4) {
            float a[4][4], b[4][4];
            #pragma unroll
            for (int rr = 0; rr < 4; ++rr) ld4(a[rr], &s_q[(tY + 16 * rr) * SW + d]);
            #pragma unroll
            for (int cc = 0; cc < 4; ++cc) ld4(b[cc], &s_k[(tX + 16 * cc) * SW + d]);
            #pragma unroll
            for (int rr = 0; rr < 4; ++rr)
                #pragma unroll
                for (int cc = 0; cc < 4; ++cc)
                    #pragma unroll
                    for (int u = 0; u < 4; ++u)
                        acc[rr][cc] = fmaf(a[rr][u], b[cc][u], acc[rr][cc]);
        }
    }
    #pragma unroll
    for (int rr = 0; rr < 4; ++rr)
        #pragma unroll
        for (int cc = 0; cc < 4; ++cc) {
            int row = n0 + tY + 16 * rr;
            int col = m0 + tX + 16 * cc;
            long idx = (long)h * (kN * kN) + (long)row * kN + col;
            logits[idx] = acc[rr][cc] * kScale + diffs[idx];
        }
}

// ---------------- softmax over m, per (h,n) row ----------------
__global__ __launch_bounds__(256) void softmax_kernel(float* __restrict__ logits)
{
    const int row = blockIdx.x;
    float* p = logits + (long)row * kN;
    const int t = threadIdx.x;
    float v0 = p[t];
    float v1 = p[t + 256];
    float m = fmaxf(v0, v1);
    #pragma unroll
    for (int off = 32; off > 0; off >>= 1) m = fmaxf(m, __shfl_xor(m, off));
    __shared__ float s_red[4];
    __shared__ float s_sum[4];
    if ((t & 63) == 0) s_red[t >> 6] = m;
    __syncthreads();
    m = fmaxf(fmaxf(s_red[0], s_red[1]), fmaxf(s_red[2], s_red[3]));
    float e0 = expf(v0 - m);
    float e1 = expf(v1 - m);
    float s = e0 + e1;
    #pragma unroll
    for (int off = 32; off > 0; off >>= 1) s += __shfl_xor(s, off);
    if ((t & 63) == 0) s_sum[t >> 6] = s;
    __syncthreads();
    s = (s_sum[0] + s_sum[1]) + (s_sum[2] + s_sum[3]);
    float inv = 1.0f / s;
    p[t] = e0 * inv;
    p[t + 256] = e1 * inv;
}

// ---------------- vals[n, h*128+d] = sum_m attn[h,n,m]*v[m,h,d] -------------
__global__ __launch_bounds__(256) void attnv_kernel(
    const float* __restrict__ attn, const float* __restrict__ qkv,
    float* __restrict__ vals)
{
    constexpr int SW = 68;
    __shared__ float s_p[32 * SW];
    __shared__ float s_v[64 * SW];
    const int t  = threadIdx.x;
    const int tx = t & 15;
    const int ty = t >> 4;
    const int h  = blockIdx.z;
    const int n0 = blockIdx.x * 32;
    const int d0 = blockIdx.y * 64;

    float acc[2][4];
    #pragma unroll
    for (int a = 0; a < 2; ++a)
        #pragma unroll
        for (int b = 0; b < 4; ++b) acc[a][b] = 0.0f;

    for (int mt = 0; mt < 8; ++mt) {
        const int m0 = mt * 64;
        __syncthreads();
        #pragma unroll
        for (int rep = 0; rep < 2; ++rep) {
            int f = rep * 256 + t;
            int row = f >> 4;
            int c4  = f & 15;
            *(float4*)&s_p[row * SW + c4 * 4] =
                *(const float4*)&attn[(long)h * (kN * kN) + (long)(n0 + row) * kN + m0 + c4 * 4];
        }
        #pragma unroll
        for (int rep = 0; rep < 4; ++rep) {
            int f = rep * 256 + t;
            int row = f >> 4;
            int c4  = f & 15;
            *(float4*)&s_v[row * SW + c4 * 4] =
                *(const float4*)&qkv[(m0 + row) * (3 * kHHD) + h * 384 + 256 + d0 + c4 * 4];
        }
        __syncthreads();
        for (int kk = 0; kk < 64; kk += 4) {
            float a[2][4], b[4][4];
            #pragma unroll
            for (int rr = 0; rr < 2; ++rr) ld4(a[rr], &s_p[(ty + 16 * rr) * SW + kk]);
            #pragma unroll
            for (int u = 0; u < 4; ++u) ld4(b[u], &s_v[(kk + u) * SW + 4 * tx]);
            #pragma unroll
            for (int rr = 0; rr < 2; ++rr)
                #pragma unroll
                for (int cc = 0; cc < 4; ++cc)
                    #pragma unroll
                    for (int u = 0; u < 4; ++u)
                        acc[rr][cc] = fmaf(a[rr][u], b[u][cc], acc[rr][cc]);
        }
    }
    #pragma unroll
    for (int rr = 0; rr < 2; ++rr) {
        float4 o = make_float4(acc[rr][0], acc[rr][1], acc[rr][2], acc[rr][3]);
        *(float4*)&vals[(long)(n0 + ty + 16 * rr) * kHHD + h * kHD + d0 + 4 * tx] = o;
    }
}

// ---------------- x = LN2(x + vals@o_W + o_b) ----------------
__global__ __launch_bounds__(64) void oproj_ln_kernel(
    const float* __restrict__ vals, const float* __restrict__ o_W,
    const float* __restrict__ o_b, const float* __restrict__ g2,
    const float* __restrict__ b2, float* __restrict__ x)
{
    const int n = blockIdx.x;
    const int d = threadIdx.x;
    __shared__ float s_v[kHHD];
    #pragma unroll
    for (int r = 0; r < kHHD / kD; ++r) s_v[r * kD + d] = vals[n * kHHD + r * kD + d];
    __syncthreads();
    float acc = o_b[d];
    for (int j = 0; j < kHHD; ++j) acc = fmaf(s_v[j], o_W[j * kD + d], acc);
    float xv = x[n * kD + d] + acc;
    float mu = xv;
    #pragma unroll
    for (int off = 32; off > 0; off >>= 1) mu += __shfl_xor(mu, off);
    mu *= (1.0f / kD);
    float dv = xv - mu;
    float var = dv * dv;
    #pragma unroll
    for (int off = 32; off > 0; off >>= 1) var += __shfl_xor(var, off);
    var *= (1.0f / kD);
    x[n * kD + d] = dv * rsqrtf(var + kEps) * g2[d] + b2[d];
}

// ---------------- out = x @ out_W + out_b ----------------
__global__ __launch_bounds__(64) void final_kernel(
    const float* __restrict__ x, const float* __restrict__ out_W,
    const float* __restrict__ out_b, float* __restrict__ out)
{
    const int n = blockIdx.x * 64 + threadIdx.x;
    float acc = out_b[0];
    #pragma unroll
    for (int d = 0; d < kD; ++d) acc = fmaf(x[n * kD + d], out_W[d], acc);
    out[n] = acc;
}

} // anonymous namespace

extern "C" void kernel_launch(void* const* d_in, const int* in_sizes, int n_in,
                              void* d_out, int out_size, void* d_ws, size_t ws_size,
                              hipStream_t stream)
{
    (void)in_sizes; (void)n_in; (void)out_size; (void)ws_size;

    const float* nf     = (const float*)d_in[0];
    const float* amds   = (const float*)d_in[1];
    const float* emb_W  = (const float*)d_in[2];
    const float* emb_b  = (const float*)d_in[3];
    const float* bemb_W = (const float*)d_in[4];
    const float* bemb_b = (const float*)d_in[5];
    const float* ln1_g  = (const float*)d_in[6];
    const float* ln1_b  = (const float*)d_in[7];
    const float* ln2_g  = (const float*)d_in[8];
    const float* ln2_b  = (const float*)d_in[9];
    const float* qkv_W  = (const float*)d_in[10];
    const float* qkv_b  = (const float*)d_in[11];
    const float* diff_W = (const float*)d_in[12];
    const float* diff_b = (const float*)d_in[13];
    const float* o_W    = (const float*)d_in[14];
    const float* o_b    = (const float*)d_in[15];
    const float* bout_W = (const float*)d_in[16];
    const float* bout_b = (const float*)d_in[17];
    const float* out_W  = (const float*)d_in[18];
    const float* out_b  = (const float*)d_in[19];

    float* ws = (float*)d_ws;
    float* ws_x      = ws;                   // 512*64
    float* ws_b0     = ws_x + 32768;         // 512*64
    float* ws_qkv    = ws_b0 + 32768;        // 512*1536
    float* ws_vals   = ws_qkv + 786432;      // 512*512
    float* ws_diffs  = ws_vals + 262144;     // 4*512*512
    float* ws_logits = ws_diffs + 1048576;   // 4*512*512
    float* ws_bias   = ws_logits + 1048576;  // 512*512*64
    u16*   ws_u      = (u16*)(ws_bias + 16777216);
    u16* dWt    = ws_u;                      // 4*512*64  fp16
    u16* boutWt = dWt + 131072;              // 4*64*512  fp16

    embed_kernel<<<kN, kD, 0, stream>>>(nf, amds, emb_W, emb_b, bemb_W, bemb_b,
                                        ln1_g, ln1_b, ws_x, ws_b0);
    bias_init_kernel<<<(kN * kN * kD / 4) / 256, 256, 0, stream>>>(
        ws_b0, (float4*)ws_bias);
    prep_weights_kernel<<<(2 * 4 * 32768) / 256, 256, 0, stream>>>(
        diff_W, bout_W, dWt, boutWt);

    for (int l = 0; l < 4; ++l) {
        qkv_kernel<<<dim3(6, kN), 256, 0, stream>>>(
            ws_x, qkv_W + l * kD * (3 * kHHD), qkv_b + l * (3 * kHHD), ws_qkv);
        bias_layer_mfma<<<kN * kN / 128, 256, 0, stream>>>(
            ws_bias, dWt + l * 32768, boutWt + l * 32768,
            diff_b + l * kHHD, bout_b + l * kD, ws_diffs);
        logits_kernel<<<dim3(8, 8, kH), 256, 0, stream>>>(ws_qkv, ws_diffs, ws_logits);
        softmax_kernel<<<kH * kN, 256, 0, stream>>>(ws_logits);
        attnv_kernel<<<dim3(16, 2, kH), 256, 0, stream>>>(ws_logits, ws_qkv, ws_vals);
        oproj_ln_kernel<<<kN, kD, 0, stream>>>(
            ws_vals, o_W + l * kHHD * kD, o_b + l * kD, ln2_g, ln2_b, ws_x);
    }
    final_kernel<<<kN / kD, kD, 0, stream>>>(ws_x, out_W, out_b, (float*)d_out);
}

// Round 10
// 618.102 us; speedup vs baseline: 4.8545x; 1.1127x over previous
//
#include <hip/hip_runtime.h>
#include <hip/hip_bf16.h>
#include <hip/hip_fp16.h>
#include <cmath>

// CrAKN fused implementation.
// R10 = R9 (fp16 MFMA bias chain) + (a) bias persisted as fp16 end-to-end
// (bit-identical math: GEMM1 rounded bias to fp16 anyway; the round just
// moves to the store side) halving bias HBM traffic, and (b) the dead
// last-layer bias update skipped (only diffs are consumed from layer 3).

namespace {

constexpr int kN   = 512;
constexpr int kD   = 64;
constexpr int kH   = 4;
constexpr int kHD  = 128;
constexpr int kHHD = 512;
constexpr int kFB  = 256;
constexpr int kK   = 100;
constexpr float kEps   = 1e-5f;
constexpr float kScale = 0.08838834764831845f; // 1/sqrt(128)

typedef unsigned short u16;
typedef unsigned int u32;
typedef short bf16x8 __attribute__((ext_vector_type(8)));   // raw 16B container
typedef _Float16 f16x8 __attribute__((ext_vector_type(8)));
typedef float f32x4 __attribute__((ext_vector_type(4)));

// mish(x) = x - 2x*rcp(e*(e+2)+2), e = exp(x)  (exact identity)
__device__ __forceinline__ float mish_f(float x) {
    float e  = __expf(fminf(x, 15.0f));
    float n2 = fmaf(e, e + 2.0f, 2.0f);
    return fmaf(x + x, -__builtin_amdgcn_rcpf(n2), x);
}

__device__ __forceinline__ u32 pkh(float a, float b) {
    union { __half2 h; u32 u; } cv;
    cv.h = __float22half2_rn(make_float2(a, b));
    return cv.u; // a low 16, b high 16
}
__device__ __forceinline__ f16x8 mkh8(u32 a, u32 b, u32 c, u32 d) {
    union { u32 w[4]; f16x8 v; } cv;
    cv.w[0] = a; cv.w[1] = b; cv.w[2] = c; cv.w[3] = d;
    return cv.v;
}
__device__ __forceinline__ u16 f16_bits(float f) {
    union { __half h; u16 u; } cv;
    cv.h = __float2half(f);
    return cv.u;
}

__device__ __forceinline__ void ld4(float* d, const float* s) {
    float4 v = *(const float4*)s;
    d[0] = v.x; d[1] = v.y; d[2] = v.z; d[3] = v.w;
}

// ---------------- embed + LN1, and b0 = amds @ bias_emb ----------------
__global__ __launch_bounds__(64) void embed_kernel(
    const float* __restrict__ nf, const float* __restrict__ amds,
    const float* __restrict__ emb_W, const float* __restrict__ emb_b,
    const float* __restrict__ bemb_W, const float* __restrict__ bemb_b,
    const float* __restrict__ ln1_g, const float* __restrict__ ln1_b,
    float* __restrict__ x, float* __restrict__ b0)
{
    const int n = blockIdx.x;
    const int d = threadIdx.x;
    __shared__ float s_row[kFB];
    #pragma unroll
    for (int r = 0; r < kFB / kD; ++r) s_row[r * kD + d] = nf[n * kFB + r * kD + d];
    __syncthreads();
    float acc = emb_b[d];
    for (int k = 0; k < kFB; ++k) acc = fmaf(s_row[k], emb_W[k * kD + d], acc);
    float mu = acc;
    #pragma unroll
    for (int off = 32; off > 0; off >>= 1) mu += __shfl_xor(mu, off);
    mu *= (1.0f / kD);
    float dv = acc - mu;
    float var = dv * dv;
    #pragma unroll
    for (int off = 32; off > 0; off >>= 1) var += __shfl_xor(var, off);
    var *= (1.0f / kD);
    x[n * kD + d] = dv * rsqrtf(var + kEps) * ln1_g[d] + ln1_b[d];
    __syncthreads();
    s_row[d] = amds[n * kK + d];
    if (d < kK - kD) s_row[kD + d] = amds[n * kK + kD + d];
    __syncthreads();
    float bacc = bemb_b[d];
    for (int k = 0; k < kK; ++k) bacc = fmaf(s_row[k], bemb_W[k * kD + d], bacc);
    b0[n * kD + d] = bacc;
}

// ---------------- bias[i,j,d] = fp16(b0[j,d] - b0[i,d]) ----------------
// gid covers N*N*64/8 groups of 8 elements; gid = i*4096 + j*8 + d8.
__global__ __launch_bounds__(256) void bias_init_kernel(
    const float* __restrict__ b0, u16* __restrict__ bias)
{
    int gid = blockIdx.x * 256 + threadIdx.x;
    int d8 = gid & 7;
    int j  = (gid >> 3) & (kN - 1);
    int i  = gid >> 12;
    const float4* bj = (const float4*)(b0 + j * kD + d8 * 8);
    const float4* bi = (const float4*)(b0 + i * kD + d8 * 8);
    float4 a0 = bj[0], a1 = bj[1];
    float4 c0 = bi[0], c1 = bi[1];
    union { u32 w[4]; bf16x8 v; } cv;
    cv.w[0] = pkh(a0.x - c0.x, a0.y - c0.y);
    cv.w[1] = pkh(a0.z - c0.z, a0.w - c0.w);
    cv.w[2] = pkh(a1.x - c1.x, a1.y - c1.y);
    cv.w[3] = pkh(a1.z - c1.z, a1.w - c1.w);
    *(bf16x8*)(bias + (long)gid * 8) = cv.v;
}

// ---------------- per-launch weight prep: transpose + fp16 ----------------
__global__ __launch_bounds__(256) void prep_weights_kernel(
    const float* __restrict__ diff_W, const float* __restrict__ bout_W,
    u16* __restrict__ dWt, u16* __restrict__ boutWt)
{
    int gid = blockIdx.x * 256 + threadIdx.x; // 2 * 4 * 32768
    if (gid < 4 * 32768) {
        int e = gid;
        int l = e >> 15;
        int r = e & 32767;
        int k = r >> 9;
        int n = r & 511;
        dWt[l * 32768 + n * 64 + k] = f16_bits(diff_W[e]);
    } else {
        int e = gid - 4 * 32768;
        int l = e >> 15;
        int r = e & 32767;
        int k = r >> 6;
        int d = r & 63;
        boutWt[l * 32768 + d * 512 + k] = f16_bits(bout_W[e]);
    }
}

// ---------------- qkv = x @ qkv_W[l] + qkv_b[l] ----------------
__global__ __launch_bounds__(256) void qkv_kernel(
    const float* __restrict__ x, const float* __restrict__ W,
    const float* __restrict__ b, float* __restrict__ qkv)
{
    const int n = blockIdx.y;
    const int c = blockIdx.x * 256 + threadIdx.x;
    __shared__ float s_x[kD];
    if (threadIdx.x < kD) s_x[threadIdx.x] = x[n * kD + threadIdx.x];
    __syncthreads();
    float acc = b[c];
    #pragma unroll 8
    for (int d = 0; d < kD; ++d) acc = fmaf(s_x[d], W[d * (3 * kHHD) + c], acc);
    qkv[n * (3 * kHHD) + c] = acc;
}

// ---------------- fused pair-bias chain, fp16 MFMA ----------
// Block = 128 pairs (4 waves x 32). Per 32-becol group-pair g2:
//   GEMM1 (be^T): A = W1^T rows permuted so that the C output at lane (q,c),
//   tile u, reg r holds be[pair=c][bc = 32*g2 + 8q + 4u + r] == the A-frag
//   element k=quad*8+j (j=4u+r) for GEMM2 (16x16x32; layout dtype-indep).
//   GEMM2: acc2 += be_chunk @ W2 chunk (skipped when last: bias dead).
// bias is fp16 in global (B-frags load raw). LDS stages W1/W2 fp16 chunks
// (XOR-swizzled, double-buffered), 1 barrier/g2.
__global__ __launch_bounds__(256, 4) void bias_layer_mfma(
    u16* __restrict__ bias,
    const u16* __restrict__ dWt, const u16* __restrict__ boutWt,
    const float* __restrict__ diff_b, const float* __restrict__ bout_b,
    float* __restrict__ diffs, int last)
{
    // [buf][ w1: 32 rows * 64 u16 | w2 at 2048: 64 rows * 32 u16 ]
    __shared__ u16 s_w[2][4096]; // 16 KB

    const int t    = threadIdx.x;
    const int w    = t >> 6;
    const int lane = t & 63;
    const int q    = lane >> 4;    // quad
    const int c    = lane & 15;
    const int pb   = blockIdx.x * 128 + w * 32;  // wave's 32 pairs

    // --- staging indices (per thread): W1 row-permuted + k-block XOR swizzle
    const int sb_bc  = t >> 3;       // source W1^T row within chunk (0..31)
    const int sb_kb  = t & 7;        // k block (8 u16 each)
    const int sr     = ((sb_bc >> 2) & 1) * 16 + ((sb_bc >> 3) << 2) + (sb_bc & 3);
    const int w1_dst = sr * 64 + (sb_kb ^ (sr & 7)) * 8;
    const int sb_d   = t >> 2;       // W2 row d (0..63)
    const int sb_k2  = t & 3;        // k block within 32
    const int w2_dst = 2048 + sb_d * 32 + (sb_k2 ^ ((sb_d >> 1) & 3)) * 8;
    const u16* g_w1 = dWt + sb_bc * 64 + sb_kb * 8;
    const u16* g_w2 = boutWt + sb_d * 512 + sb_k2 * 8;

    // --- B-frags: bias^T (fp16, raw load) for two 16-pair tiles, K=64
    f16x8 Bf[2][2];
    #pragma unroll
    for (int mt = 0; mt < 2; ++mt) {
        #pragma unroll
        for (int s = 0; s < 2; ++s) {
            Bf[mt][s] = *(const f16x8*)(bias + (long)(pb + mt * 16 + c) * kD + s * 32 + q * 8);
        }
    }

    // --- prologue stage g2=0 into buf 0
    {
        bf16x8 r0 = *(const bf16x8*)g_w1;
        bf16x8 r1 = *(const bf16x8*)g_w2;
        *(bf16x8*)&s_w[0][w1_dst] = r0;
        *(bf16x8*)&s_w[0][w2_dst] = r1;
    }
    __syncthreads();

    f32x4 acc2[2][4];
    #pragma unroll
    for (int mt = 0; mt < 2; ++mt)
        #pragma unroll
        for (int dg = 0; dg < 4; ++dg) acc2[mt][dg] = (f32x4)0.0f;
    float psum[2][4];
    #pragma unroll
    for (int mt = 0; mt < 2; ++mt)
        #pragma unroll
        for (int h = 0; h < 4; ++h) psum[mt][h] = 0.0f;

    const int sw1 = c & 7;          // W1 read swizzle key
    const int sw2 = (c >> 1) & 3;   // W2 read swizzle key
    int cur = 0;

    for (int g2 = 0; g2 < 16; ++g2) {
        // prefetch next weight chunk into regs (committed after compute)
        bf16x8 r0, r1;
        if (g2 < 15) {
            r0 = *(const bf16x8*)(g_w1 + (g2 + 1) * 2048);
            r1 = *(const bf16x8*)(g_w2 + (g2 + 1) * 32);
        }

        // ---- GEMM1: a1[mt][u] = W1^T(permuted rows) x bias^T  (fp16)
        f32x4 a1[2][2];
        #pragma unroll
        for (int mt = 0; mt < 2; ++mt)
            #pragma unroll
            for (int u = 0; u < 2; ++u) a1[mt][u] = (f32x4)0.0f;
        const u16* w1 = &s_w[cur][0];
        #pragma unroll
        for (int u = 0; u < 2; ++u) {
            int row = (u * 16 + c) * 64;
            int o0 = row + ((0 + q) ^ sw1) * 8; // s=0 (k 0..31)
            int o1 = row + ((4 + q) ^ sw1) * 8; // s=1 (k 32..63)
            f16x8 A0 = *(const f16x8*)(w1 + o0);
            f16x8 A1 = *(const f16x8*)(w1 + o1);
            #pragma unroll
            for (int mt = 0; mt < 2; ++mt) {
                a1[mt][u] = __builtin_amdgcn_mfma_f32_16x16x32_f16(A0, Bf[mt][0], a1[mt][u], 0, 0, 0);
                a1[mt][u] = __builtin_amdgcn_mfma_f32_16x16x32_f16(A1, Bf[mt][1], a1[mt][u], 0, 0, 0);
            }
        }

        // ---- mish + psum + fp16 pack; C-layout IS GEMM2 A-layout (j = 4u+r)
        const int hd = g2 >> 2;
        f16x8 A2[2];
        #pragma unroll
        for (int mt = 0; mt < 2; ++mt) {
            u32 p[2][2];
            #pragma unroll
            for (int u = 0; u < 2; ++u) {
                float4 db = *(const float4*)(diff_b + g2 * 32 + q * 8 + u * 4);
                float v0 = mish_f(a1[mt][u][0] + db.x);
                float v1 = mish_f(a1[mt][u][1] + db.y);
                float v2 = mish_f(a1[mt][u][2] + db.z);
                float v3 = mish_f(a1[mt][u][3] + db.w);
                psum[mt][hd] += v0 * v0 + v1 * v1 + v2 * v2 + v3 * v3;
                p[u][0] = pkh(v0, v1);
                p[u][1] = pkh(v2, v3);
            }
            A2[mt] = mkh8(p[0][0], p[0][1], p[1][0], p[1][1]);
        }

        // ---- GEMM2: acc2 += be_chunk @ W2 chunk (fp16); dead in last layer
        if (!last) {
            const u16* w2 = &s_w[cur][2048];
            const int kb2 = (q ^ sw2) * 8;
            #pragma unroll
            for (int dg = 0; dg < 4; ++dg) {
                int bo = dg * 512 + c * 32 + kb2;
                f16x8 Wf = *(const f16x8*)(w2 + bo);
                #pragma unroll
                for (int mt = 0; mt < 2; ++mt) {
                    acc2[mt][dg] = __builtin_amdgcn_mfma_f32_16x16x32_f16(A2[mt], Wf, acc2[mt][dg], 0, 0, 0);
                }
            }
        }

        // ---- commit prefetched chunk, flip buffers
        if (g2 < 15) {
            int nb = cur ^ 1;
            *(bf16x8*)&s_w[nb][w1_dst] = r0;
            *(bf16x8*)&s_w[nb][w2_dst] = r1;
            __syncthreads();
            cur = nb;
        }
    }

    // ---- epilogue: bias tile in place (fp16) + diffs
    if (!last) {
        #pragma unroll
        for (int mt = 0; mt < 2; ++mt) {
            #pragma unroll
            for (int dg = 0; dg < 4; ++dg) {
                float bb = bout_b[dg * 16 + c];
                #pragma unroll
                for (int r = 0; r < 4; ++r) {
                    float v = mish_f(acc2[mt][dg][r] + bb);
                    bias[(long)(pb + mt * 16 + 4 * q + r) * kD + dg * 16 + c] = f16_bits(v);
                }
            }
        }
    }
    const int i  = blockIdx.x >> 2;
    const int jb = (blockIdx.x & 3) * 128 + w * 32;
    #pragma unroll
    for (int mt = 0; mt < 2; ++mt) {
        #pragma unroll
        for (int h = 0; h < 4; ++h) {
            psum[mt][h] += __shfl_xor(psum[mt][h], 16);
            psum[mt][h] += __shfl_xor(psum[mt][h], 32);
        }
        float sv = (q == 0) ? psum[mt][0] : (q == 1) ? psum[mt][1]
                 : (q == 2) ? psum[mt][2] : psum[mt][3];
        diffs[q * (kN * kN) + i * kN + jb + mt * 16 + c] = sqrtf(sv);
    }
}

// ---------------- logits[h,n,m] = scale*q.k + diffs ----------------
__global__ __launch_bounds__(256) void logits_kernel(
    const float* __restrict__ qkv, const float* __restrict__ diffs,
    float* __restrict__ logits)
{
    constexpr int SW = 68;
    __shared__ float s_q[64 * SW];
    __shared__ float s_k[64 * SW];
    const int t  = threadIdx.x;
    const int tX = t & 15;
    const int tY = t >> 4;
    const int h  = blockIdx.z;
    const int n0 = blockIdx.x * 64;
    const int m0 = blockIdx.y * 64;

    float acc[4][4];
    #pragma unroll
    for (int a = 0; a < 4; ++a)
        #pragma unroll
        for (int b = 0; b < 4; ++b) acc[a][b] = 0.0f;

    for (int dc = 0; dc < 2; ++dc) {
        __syncthreads();
        #pragma unroll
        for (int rep = 0; rep < 4; ++rep) {
            int f = rep * 256 + t;
            int row = f >> 4;
            int c4  = f & 15;
            *(float4*)&s_q[row * SW + c4 * 4] =
                *(const float4*)&qkv[(n0 + row) * (3 * kHHD) + h * 384 + dc * 64 + c4 * 4];
            *(float4*)&s_k[row * SW + c4 * 4] =
                *(const float4*)&qkv[(m0 + row) * (3 * kHHD) + h * 384 + 128 + dc * 64 + c4 * 4];
        }
        __syncthreads();
        for (int d = 0; d < 64; d += 4) {
            float a[4][4], b[4][4];
            #pragma unroll
            for (int rr = 0; rr < 4; ++rr) ld4(a[rr], &s_q[(tY + 16 * rr) * SW + d]);
            #pragma unroll
            for (int cc = 0; cc < 4; ++cc) ld4(b[cc], &s_k[(tX + 16 * cc) * SW + d]);
            #pragma unroll
            for (int rr = 0; rr < 4; ++rr)
                #pragma unroll
                for (int cc = 0; cc < 4; ++cc)
                    #pragma unroll
                    for (int u = 0; u < 4; ++u)
                        acc[rr][cc] = fmaf(a[rr][u], b[cc][u], acc[rr][cc]);
        }
    }
    #pragma unroll
    for (int rr = 0; rr < 4; ++rr)
        #pragma unroll
        for (int cc = 0; cc < 4; ++cc) {
            int row = n0 + tY + 16 * rr;
            int col = m0 + tX + 16 * cc;
            long idx = (long)h * (kN * kN) + (long)row * kN + col;
            logits[idx] = acc[rr][cc] * kScale + diffs[idx];
        }
}

// ---------------- softmax over m, per (h,n) row ----------------
__global__ __launch_bounds__(256) void softmax_kernel(float* __restrict__ logits)
{
    const int row = blockIdx.x;
    float* p = logits + (long)row * kN;
    const int t = threadIdx.x;
    float v0 = p[t];
    float v1 = p[t + 256];
    float m = fmaxf(v0, v1);
    #pragma unroll
    for (int off = 32; off > 0; off >>= 1) m = fmaxf(m, __shfl_xor(m, off));
    __shared__ float s_red[4];
    __shared__ float s_sum[4];
    if ((t & 63) == 0) s_red[t >> 6] = m;
    __syncthreads();
    m = fmaxf(fmaxf(s_red[0], s_red[1]), fmaxf(s_red[2], s_red[3]));
    float e0 = expf(v0 - m);
    float e1 = expf(v1 - m);
    float s = e0 + e1;
    #pragma unroll
    for (int off = 32; off > 0; off >>= 1) s += __shfl_xor(s, off);
    if ((t & 63) == 0) s_sum[t >> 6] = s;
    __syncthreads();
    s = (s_sum[0] + s_sum[1]) + (s_sum[2] + s_sum[3]);
    float inv = 1.0f / s;
    p[t] = e0 * inv;
    p[t + 256] = e1 * inv;
}

// ---------------- vals[n, h*128+d] = sum_m attn[h,n,m]*v[m,h,d] -------------
__global__ __launch_bounds__(256) void attnv_kernel(
    const float* __restrict__ attn, const float* __restrict__ qkv,
    float* __restrict__ vals)
{
    constexpr int SW = 68;
    __shared__ float s_p[32 * SW];
    __shared__ float s_v[64 * SW];
    const int t  = threadIdx.x;
    const int tx = t & 15;
    const int ty = t >> 4;
    const int h  = blockIdx.z;
    const int n0 = blockIdx.x * 32;
    const int d0 = blockIdx.y * 64;

    float acc[2][4];
    #pragma unroll
    for (int a = 0; a < 2; ++a)
        #pragma unroll
        for (int b = 0; b < 4; ++b) acc[a][b] = 0.0f;

    for (int mt = 0; mt < 8; ++mt) {
        const int m0 = mt * 64;
        __syncthreads();
        #pragma unroll
        for (int rep = 0; rep < 2; ++rep) {
            int f = rep * 256 + t;
            int row = f >> 4;
            int c4  = f & 15;
            *(float4*)&s_p[row * SW + c4 * 4] =
                *(const float4*)&attn[(long)h * (kN * kN) + (long)(n0 + row) * kN + m0 + c4 * 4];
        }
        #pragma unroll
        for (int rep = 0; rep < 4; ++rep) {
            int f = rep * 256 + t;
            int row = f >> 4;
            int c4  = f & 15;
            *(float4*)&s_v[row * SW + c4 * 4] =
                *(const float4*)&qkv[(m0 + row) * (3 * kHHD) + h * 384 + 256 + d0 + c4 * 4];
        }
        __syncthreads();
        for (int kk = 0; kk < 64; kk += 4) {
            float a[2][4], b[4][4];
            #pragma unroll
            for (int rr = 0; rr < 2; ++rr) ld4(a[rr], &s_p[(ty + 16 * rr) * SW + kk]);
            #pragma unroll
            for (int u = 0; u < 4; ++u) ld4(b[u], &s_v[(kk + u) * SW + 4 * tx]);
            #pragma unroll
            for (int rr = 0; rr < 2; ++rr)
                #pragma unroll
                for (int cc = 0; cc < 4; ++cc)
                    #pragma unroll
                    for (int u = 0; u < 4; ++u)
                        acc[rr][cc] = fmaf(a[rr][u], b[u][cc], acc[rr][cc]);
        }
    }
    #pragma unroll
    for (int rr = 0; rr < 2; ++rr) {
        float4 o = make_float4(acc[rr][0], acc[rr][1], acc[rr][2], acc[rr][3]);
        *(float4*)&vals[(long)(n0 + ty + 16 * rr) * kHHD + h * kHD + d0 + 4 * tx] = o;
    }
}

// ---------------- x = LN2(x + vals@o_W + o_b) ----------------
__global__ __launch_bounds__(64) void oproj_ln_kernel(
    const float* __restrict__ vals, const float* __restrict__ o_W,
    const float* __restrict__ o_b, const float* __restrict__ g2,
    const float* __restrict__ b2, float* __restrict__ x)
{
    const int n = blockIdx.x;
    const int d = threadIdx.x;
    __shared__ float s_v[kHHD];
    #pragma unroll
    for (int r = 0; r < kHHD / kD; ++r) s_v[r * kD + d] = vals[n * kHHD + r * kD + d];
    __syncthreads();
    float acc = o_b[d];
    for (int j = 0; j < kHHD; ++j) acc = fmaf(s_v[j], o_W[j * kD + d], acc);
    float xv = x[n * kD + d] + acc;
    float mu = xv;
    #pragma unroll
    for (int off = 32; off > 0; off >>= 1) mu += __shfl_xor(mu, off);
    mu *= (1.0f / kD);
    float dv = xv - mu;
    float var = dv * dv;
    #pragma unroll
    for (int off = 32; off > 0; off >>= 1) var += __shfl_xor(var, off);
    var *= (1.0f / kD);
    x[n * kD + d] = dv * rsqrtf(var + kEps) * g2[d] + b2[d];
}

// ---------------- out = x @ out_W + out_b ----------------
__global__ __launch_bounds__(64) void final_kernel(
    const float* __restrict__ x, const float* __restrict__ out_W,
    const float* __restrict__ out_b, float* __restrict__ out)
{
    const int n = blockIdx.x * 64 + threadIdx.x;
    float acc = out_b[0];
    #pragma unroll
    for (int d = 0; d < kD; ++d) acc = fmaf(x[n * kD + d], out_W[d], acc);
    out[n] = acc;
}

} // anonymous namespace

extern "C" void kernel_launch(void* const* d_in, const int* in_sizes, int n_in,
                              void* d_out, int out_size, void* d_ws, size_t ws_size,
                              hipStream_t stream)
{
    (void)in_sizes; (void)n_in; (void)out_size; (void)ws_size;

    const float* nf     = (const float*)d_in[0];
    const float* amds   = (const float*)d_in[1];
    const float* emb_W  = (const float*)d_in[2];
    const float* emb_b  = (const float*)d_in[3];
    const float* bemb_W = (const float*)d_in[4];
    const float* bemb_b = (const float*)d_in[5];
    const float* ln1_g  = (const float*)d_in[6];
    const float* ln1_b  = (const float*)d_in[7];
    const float* ln2_g  = (const float*)d_in[8];
    const float* ln2_b  = (const float*)d_in[9];
    const float* qkv_W  = (const float*)d_in[10];
    const float* qkv_b  = (const float*)d_in[11];
    const float* diff_W = (const float*)d_in[12];
    const float* diff_b = (const float*)d_in[13];
    const float* o_W    = (const float*)d_in[14];
    const float* o_b    = (const float*)d_in[15];
    const float* bout_W = (const float*)d_in[16];
    const float* bout_b = (const float*)d_in[17];
    const float* out_W  = (const float*)d_in[18];
    const float* out_b  = (const float*)d_in[19];

    float* ws = (float*)d_ws;
    float* ws_x      = ws;                   // 512*64
    float* ws_b0     = ws_x + 32768;         // 512*64
    float* ws_qkv    = ws_b0 + 32768;        // 512*1536
    float* ws_vals   = ws_qkv + 786432;      // 512*512
    float* ws_diffs  = ws_vals + 262144;     // 4*512*512
    float* ws_logits = ws_diffs + 1048576;   // 4*512*512
    u16*   ws_bias   = (u16*)(ws_logits + 1048576); // 512*512*64 fp16 (33.5 MB)
    u16*   dWt       = ws_bias + 16777216;   // 4*512*64  fp16
    u16*   boutWt    = dWt + 131072;         // 4*64*512  fp16

    embed_kernel<<<kN, kD, 0, stream>>>(nf, amds, emb_W, emb_b, bemb_W, bemb_b,
                                        ln1_g, ln1_b, ws_x, ws_b0);
    bias_init_kernel<<<(kN * kN * kD / 8) / 256, 256, 0, stream>>>(ws_b0, ws_bias);
    prep_weights_kernel<<<(2 * 4 * 32768) / 256, 256, 0, stream>>>(
        diff_W, bout_W, dWt, boutWt);

    for (int l = 0; l < 4; ++l) {
        qkv_kernel<<<dim3(6, kN), 256, 0, stream>>>(
            ws_x, qkv_W + l * kD * (3 * kHHD), qkv_b + l * (3 * kHHD), ws_qkv);
        bias_layer_mfma<<<kN * kN / 128, 256, 0, stream>>>(
            ws_bias, dWt + l * 32768, boutWt + l * 32768,
            diff_b + l * kHHD, bout_b + l * kD, ws_diffs, (l == 3) ? 1 : 0);
        logits_kernel<<<dim3(8, 8, kH), 256, 0, stream>>>(ws_qkv, ws_diffs, ws_logits);
        softmax_kernel<<<kH * kN, 256, 0, stream>>>(ws_logits);
        attnv_kernel<<<dim3(16, 2, kH), 256, 0, stream>>>(ws_logits, ws_qkv, ws_vals);
        oproj_ln_kernel<<<kN, kD, 0, stream>>>(
            ws_vals, o_W + l * kHHD * kD, o_b + l * kD, ln2_g, ln2_b, ws_x);
    }
    final_kernel<<<kN / kD, kD, 0, stream>>>(ws_x, out_W, out_b, (float*)d_out);
}